// Round 1
// baseline (108.232 us; speedup 1.0000x reference)
//
#include <hip/hip_runtime.h>
#include <hip/hip_bf16.h>

#define NN 4096
#define DD 512
#define TILE 128
#define NCH (NN / TILE)   // 32 column chunks

typedef unsigned short u16;
typedef __attribute__((ext_vector_type(4))) float f32x4;
typedef __attribute__((ext_vector_type(8))) short bf16x8;

// ws layout (bytes):
#define OFF_DIAG ((size_t)NN * DD * 2)            // xbf: NN*DD u16
#define OFF_INC  (OFF_DIAG + (size_t)NN * 4)      // diag value f32
#define OFF_PART (OFF_INC + (size_t)NN * 4)       // include flag f32
#define OFF_RL   (OFF_PART + (size_t)NCH * NN * 5 * 4)
#define OFF_INV  (OFF_RL + (size_t)NN * 4)
// total ~6.9 MB

__device__ __forceinline__ float softplusf(float z) {
  // numerically stable softplus: max(z,0) + log1p(exp(-|z|))
  return fmaxf(z, 0.0f) + log1pf(__expf(-fabsf(z)));
}

__device__ __forceinline__ void gload_lds16(const u16* g, void* l) {
  __builtin_amdgcn_global_load_lds(
      (const __attribute__((address_space(1))) void*)g,
      (__attribute__((address_space(3))) void*)l, 16, 0, 0);
}

// ---------------------------------------------------------------------------
// prep: convert x -> bf16, and per-row exact (f64) sum of squares for the
// diagonal decision (sim[i,i] < 1.0 coin flip in the reference).
__global__ __launch_bounds__(256) void prep_kernel(
    const float* __restrict__ x, u16* __restrict__ xbf,
    float* __restrict__ dval, float* __restrict__ dinc) {
  const int wid = threadIdx.x >> 6, lane = threadIdx.x & 63;
  const int row = blockIdx.x * 4 + wid;
  const float* xr = x + (size_t)row * DD;
  u16* xb = xbf + (size_t)row * DD;
  double s = 0.0;
#pragma unroll
  for (int c = 0; c < DD / 64; ++c) {
    float v = xr[c * 64 + lane];
    s += (double)v * (double)v;
    __hip_bfloat16 b = __float2bfloat16(v);
    xb[c * 64 + lane] = *reinterpret_cast<const u16*>(&b);
  }
#pragma unroll
  for (int m = 32; m; m >>= 1) s += __shfl_xor(s, m, 64);
  if (lane == 0) {
    float sf = (float)s;
    dval[row] = sf;
    dinc[row] = (sf < 1.0f) ? 1.0f : 0.0f;  // reference: pos includes diag iff sim<1
  }
}

// ---------------------------------------------------------------------------
// main: 128x128 sim tile via bf16 MFMA, fused mask+softplus+row-reduce epilogue.
// Writes 5 partials per (col-chunk, row): {same_cnt_offdiag, pos_l, neg_l,
// same_sim_offdiag, neg_sim}. Exactly one writer per slot -> deterministic.
__global__ __launch_bounds__(256) void sim_kernel(
    const u16* __restrict__ xbf, const int* __restrict__ tg,
    float* __restrict__ part) {
  __shared__ u16 sA[TILE * 32];   // [128 rows][32 k] bf16
  __shared__ u16 sB[TILE * 32];
  __shared__ float red[2][TILE][5];

  const int t = threadIdx.x;
  const int lane = t & 63, wid = t >> 6;
  const int wR = wid >> 1, wC = wid & 1;          // 2x2 wave grid, 64x64 each
  const int q = lane >> 4, lr = lane & 15;
  const int rowBase = blockIdx.y * TILE, colBase = blockIdx.x * TILE;

  f32x4 acc[4][4] = {};

  const int r0 = t >> 2;            // 0..63
  const int kk = (t & 3) * 8;       // 0,8,16,24

  for (int kb = 0; kb < DD; kb += 32) {
    const u16* gA  = xbf + (size_t)(rowBase + r0) * DD + kb + kk;
    const u16* gB  = xbf + (size_t)(colBase + r0) * DD + kb + kk;
    char* lA = (char*)sA + wid * 1024;            // wave-uniform base + lane*16
    char* lB = (char*)sB + wid * 1024;
    gload_lds16(gA, lA);
    gload_lds16(gA + 64 * DD, lA + 4096);
    gload_lds16(gB, lB);
    gload_lds16(gB + 64 * DD, lB + 4096);
    __syncthreads();   // drains vmcnt before barrier (compiler-inserted)

    bf16x8 af[4], bg[4];
#pragma unroll
    for (int m = 0; m < 4; ++m) {
      af[m] = *reinterpret_cast<const bf16x8*>(&sA[(wR * 64 + m * 16 + lr) * 32 + q * 8]);
      bg[m] = *reinterpret_cast<const bf16x8*>(&sB[(wC * 64 + m * 16 + lr) * 32 + q * 8]);
    }
#pragma unroll
    for (int m = 0; m < 4; ++m)
#pragma unroll
      for (int n = 0; n < 4; ++n)
        acc[m][n] = __builtin_amdgcn_mfma_f32_16x16x32_bf16(af[m], bg[n], acc[m][n], 0, 0, 0);
    __syncthreads();
  }

  // epilogue: C/D layout col=lane&15, row=(lane>>4)*4+j (m89-verified).
  int tc[4];
#pragma unroll
  for (int n = 0; n < 4; ++n) tc[n] = tg[colBase + wC * 64 + n * 16 + lr];

#pragma unroll
  for (int m = 0; m < 4; ++m) {
#pragma unroll
    for (int j = 0; j < 4; ++j) {
      const int rloc = wR * 64 + m * 16 + q * 4 + j;
      const int ri = rowBase + rloc;
      const int trr = tg[ri];
      float cnt = 0.f, pl = 0.f, nl = 0.f, ss = 0.f, ns = 0.f;
#pragma unroll
      for (int n = 0; n < 4; ++n) {
        const float sim = acc[m][n][j];
        const int cj = colBase + wC * 64 + n * 16 + lr;
        const bool same = (trr == tc[n]);
        if (same) {
          if (ri != cj) {   // diagonal handled analytically in finalize
            cnt += 1.0f;
            pl += softplusf(1.0f - 2.0f * sim);
            ss += sim;
          }
        } else {
          nl += softplusf(__fmaf_rn(40.0f, sim, -20.0f));
          ns += sim;
        }
      }
      // reduce over the 16 lanes sharing this row (cols)
#pragma unroll
      for (int s = 8; s; s >>= 1) {
        cnt += __shfl_xor(cnt, s, 64);
        pl  += __shfl_xor(pl,  s, 64);
        nl  += __shfl_xor(nl,  s, 64);
        ss  += __shfl_xor(ss,  s, 64);
        ns  += __shfl_xor(ns,  s, 64);
      }
      if (lr == 0) {
        red[wC][rloc][0] = cnt; red[wC][rloc][1] = pl; red[wC][rloc][2] = nl;
        red[wC][rloc][3] = ss;  red[wC][rloc][4] = ns;
      }
    }
  }
  __syncthreads();
  for (int idx = t; idx < TILE * 5; idx += 256) {
    const int row = idx / 5, qq = idx % 5;
    part[((size_t)blockIdx.x * NN + (rowBase + row)) * 5 + qq] =
        red[0][row][qq] + red[1][row][qq];
  }
}

// ---------------------------------------------------------------------------
// finalize 1: per-row combine over 32 chunks + analytic diagonal; row 4095
// also produces last_pos/last_neg directly.
__global__ __launch_bounds__(256) void fin1_kernel(
    const float* __restrict__ part, const float* __restrict__ dval,
    const float* __restrict__ dinc, float* __restrict__ row_loss,
    float* __restrict__ inv, float* __restrict__ out) {
  const int r = blockIdx.x * 256 + threadIdx.x;
  float cnt = 0.f, pl = 0.f, nl = 0.f, ss = 0.f, ns = 0.f;
  for (int c = 0; c < NCH; ++c) {
    const float* p = part + ((size_t)c * NN + r) * 5;
    cnt += p[0]; pl += p[1]; nl += p[2]; ss += p[3]; ns += p[4];
  }
  const float inc = dinc[r], dv = dval[r];
  const float pos_cnt = cnt + inc;
  const float pos_sum = pl + inc * softplusf(1.0f - 2.0f * dv);
  const float pos_loss = pos_sum / fmaxf(pos_cnt, 1.0f);
  const float neg_cnt = 4095.0f - cnt;   // total same incl diag = cnt+1
  const float neg_loss = nl / fmaxf(neg_cnt, 1.0f);
  const bool valid = neg_cnt > 0.0f;
  row_loss[r] = valid ? (pos_loss + neg_loss) : 0.0f;
  inv[r] = valid ? 0.0f : 1.0f;
  if (r == NN - 1) {
    out[2] = (ss + inc * dv) / fmaxf(pos_cnt, 1.0f);
    out[3] = ns / fmaxf(neg_cnt, 1.0f);
  }
}

// finalize 2: deterministic tree reduce of row losses.
__global__ __launch_bounds__(1024) void fin2_kernel(
    const float* __restrict__ row_loss, const float* __restrict__ inv,
    float* __restrict__ out) {
  __shared__ double sl[1024];
  __shared__ double si[1024];
  const int t = threadIdx.x;
  double l = 0.0, iv = 0.0;
  for (int r = t; r < NN; r += 1024) { l += row_loss[r]; iv += inv[r]; }
  sl[t] = l; si[t] = iv;
  __syncthreads();
  for (int s = 512; s; s >>= 1) {
    if (t < s) { sl[t] += sl[t + s]; si[t] += si[t + s]; }
    __syncthreads();
  }
  if (t == 0) {
    out[0] = (float)(sl[0] / NN);
    out[1] = (float)(si[0] / NN);
  }
}

extern "C" void kernel_launch(void* const* d_in, const int* in_sizes, int n_in,
                              void* d_out, int out_size, void* d_ws, size_t ws_size,
                              hipStream_t stream) {
  const float* x = (const float*)d_in[0];
  const int* tg = (const int*)d_in[1];
  float* out = (float*)d_out;
  char* ws = (char*)d_ws;

  u16*   xbf      = (u16*)ws;
  float* dval     = (float*)(ws + OFF_DIAG);
  float* dinc     = (float*)(ws + OFF_INC);
  float* part     = (float*)(ws + OFF_PART);
  float* row_loss = (float*)(ws + OFF_RL);
  float* inv      = (float*)(ws + OFF_INV);

  prep_kernel<<<NN / 4, 256, 0, stream>>>(x, xbf, dval, dinc);
  dim3 grid(NCH, NCH);
  sim_kernel<<<grid, 256, 0, stream>>>(xbf, tg, part);
  fin1_kernel<<<NN / 256, 256, 0, stream>>>(part, dval, dinc, row_loss, inv, out);
  fin2_kernel<<<1, 1024, 0, stream>>>(row_loss, inv, out);
}

// Round 2
// 68.289 us; speedup vs baseline: 1.5849x; 1.5849x over previous
//
#include <hip/hip_runtime.h>
#include <hip/hip_bf16.h>

#define NN 4096
#define DD 512
#define TILE 128
#define NCH (NN / TILE)   // 32 column chunks

typedef unsigned short u16;
typedef __attribute__((ext_vector_type(4))) float f32x4;
typedef __attribute__((ext_vector_type(8))) short bf16x8;

// ws layout (bytes):
#define OFF_DVAL ((size_t)NN * DD * 2)                 // xbf: NN*DD u16
#define OFF_DINC (OFF_DVAL + (size_t)NN * 4)           // exact diag value f32
#define OFF_HIST (OFF_DINC + (size_t)NN * 4)           // include flag f32
#define OFF_LRP  (OFF_HIST + 256 * 4)                  // class histogram i32
#define OFF_PART (OFF_LRP + 16 * 2 * 4)                // last-row partials
#define OFF_RL   (OFF_PART + (size_t)NCH * NN * 2 * 4) // per-chunk {pl,nl}
#define OFF_INV  (OFF_RL + (size_t)NN * 4)
// total ~5.3 MB

__device__ __forceinline__ float softplus_fast(float z) {
  // valid for z in [-87, 87]: ln(1+e^z); 2 native transcendentals.
  return __logf(1.0f + __expf(z));
}

__device__ __forceinline__ void gload_lds16(const u16* g, void* l) {
  __builtin_amdgcn_global_load_lds(
      (const __attribute__((address_space(1))) void*)g,
      (__attribute__((address_space(3))) void*)l, 16, 0, 0);
}

// ---------------------------------------------------------------------------
// prep (3 roles by blockIdx):
//   blocks [0, NN/4): x -> bf16 + exact f64 row sum-of-squares (diag decision)
//   block NN/4:       class histogram (LDS int atomics = deterministic)
//   blocks NN/4+1 ..: last-row (4095) f32 sim partial sums {ss, ns}
__global__ __launch_bounds__(256) void prep_kernel(
    const float* __restrict__ x, const int* __restrict__ tg,
    u16* __restrict__ xbf, float* __restrict__ dval, float* __restrict__ dinc,
    int* __restrict__ hist, float* __restrict__ lrp) {
  const int bid = blockIdx.x;
  const int t = threadIdx.x;
  if (bid < NN / 4) {
    const int wid = t >> 6, lane = t & 63;
    const int row = bid * 4 + wid;
    const float* xr = x + (size_t)row * DD;
    u16* xb = xbf + (size_t)row * DD;
    double s = 0.0;
#pragma unroll
    for (int c = 0; c < DD / 64; ++c) {
      float v = xr[c * 64 + lane];
      s += (double)v * (double)v;
      __hip_bfloat16 b = __float2bfloat16(v);
      xb[c * 64 + lane] = *reinterpret_cast<const u16*>(&b);
    }
#pragma unroll
    for (int m = 32; m; m >>= 1) s += __shfl_xor(s, m, 64);
    if (lane == 0) {
      float sf = (float)s;
      dval[row] = sf;
      dinc[row] = (sf < 1.0f) ? 1.0f : 0.0f;  // ref: pos includes diag iff sim<1
    }
  } else if (bid == NN / 4) {
    __shared__ int h[256];
    h[t] = 0;
    __syncthreads();
    const int base = t * (NN / 256);
#pragma unroll
    for (int k = 0; k < NN / 256; ++k) atomicAdd(&h[tg[base + k]], 1);
    __syncthreads();
    hist[t] = h[t];
  } else {
    const int b = bid - (NN / 4 + 1);
    const int j = b * 256 + t;
    const int tl = tg[NN - 1];
    const f32x4* xr = (const f32x4*)(x + (size_t)(NN - 1) * DD);
    const f32x4* xj = (const f32x4*)(x + (size_t)j * DD);
    f32x4 av = {0.f, 0.f, 0.f, 0.f};
#pragma unroll 4
    for (int k = 0; k < DD / 4; ++k) av += xr[k] * xj[k];
    const float sim = av[0] + av[1] + av[2] + av[3];
    const bool same = (tg[j] == tl);
    float ss = (same && j != NN - 1) ? sim : 0.0f;
    float ns = !same ? sim : 0.0f;
#pragma unroll
    for (int m = 32; m; m >>= 1) {
      ss += __shfl_xor(ss, m, 64);
      ns += __shfl_xor(ns, m, 64);
    }
    __shared__ float r2[2][4];
    if ((t & 63) == 0) { r2[0][t >> 6] = ss; r2[1][t >> 6] = ns; }
    __syncthreads();
    if (t == 0) {
      lrp[b * 2 + 0] = r2[0][0] + r2[0][1] + r2[0][2] + r2[0][3];
      lrp[b * 2 + 1] = r2[1][0] + r2[1][1] + r2[1][2] + r2[1][3];
    }
  }
}

// ---------------------------------------------------------------------------
// main: 128x128 sim tile via bf16 MFMA; fused branch-free mask+softplus
// epilogue reducing only {pos_l, neg_l} per row. One writer per slot.
__global__ __launch_bounds__(256) void sim_kernel(
    const u16* __restrict__ xbf, const int* __restrict__ tg,
    float* __restrict__ part) {
  __shared__ u16 sA[TILE * 32];   // [128 rows][32 k] bf16
  __shared__ u16 sB[TILE * 32];
  __shared__ float red[2][TILE][2];

  const int t = threadIdx.x;
  const int lane = t & 63, wid = t >> 6;
  const int wR = wid >> 1, wC = wid & 1;          // 2x2 wave grid, 64x64 each
  const int q = lane >> 4, lr = lane & 15;
  const int rowBase = blockIdx.y * TILE, colBase = blockIdx.x * TILE;

  f32x4 acc[4][4] = {};

  const int r0 = t >> 2;            // 0..63
  const int kk = (t & 3) * 8;       // 0,8,16,24

  for (int kb = 0; kb < DD; kb += 32) {
    const u16* gA = xbf + (size_t)(rowBase + r0) * DD + kb + kk;
    const u16* gB = xbf + (size_t)(colBase + r0) * DD + kb + kk;
    char* lA = (char*)sA + wid * 1024;            // wave-uniform base + lane*16
    char* lB = (char*)sB + wid * 1024;
    gload_lds16(gA, lA);
    gload_lds16(gA + 64 * DD, lA + 4096);
    gload_lds16(gB, lB);
    gload_lds16(gB + 64 * DD, lB + 4096);
    __syncthreads();

    bf16x8 af[4], bg[4];
#pragma unroll
    for (int m = 0; m < 4; ++m) {
      af[m] = *reinterpret_cast<const bf16x8*>(&sA[(wR * 64 + m * 16 + lr) * 32 + q * 8]);
      bg[m] = *reinterpret_cast<const bf16x8*>(&sB[(wC * 64 + m * 16 + lr) * 32 + q * 8]);
    }
#pragma unroll
    for (int m = 0; m < 4; ++m)
#pragma unroll
      for (int n = 0; n < 4; ++n)
        acc[m][n] = __builtin_amdgcn_mfma_f32_16x16x32_bf16(af[m], bg[n], acc[m][n], 0, 0, 0);
    __syncthreads();
  }

  // epilogue: C/D layout col=lane&15, row=(lane>>4)*4+j (m89-verified).
  int tc[4];
#pragma unroll
  for (int n = 0; n < 4; ++n) tc[n] = tg[colBase + wC * 64 + n * 16 + lr];

#pragma unroll
  for (int m = 0; m < 4; ++m) {
#pragma unroll
    for (int j = 0; j < 4; ++j) {
      const int rloc = wR * 64 + m * 16 + q * 4 + j;
      const int ri = rowBase + rloc;
      const int trr = tg[ri];
      float pl = 0.f, nl = 0.f;
#pragma unroll
      for (int n = 0; n < 4; ++n) {
        const float sim = acc[m][n][j];
        const int cj = colBase + wC * 64 + n * 16 + lr;
        const bool same = (trr == tc[n]);
        const float c = same ? -2.0f : 40.0f;
        const float sp = softplus_fast(c * (sim - 0.5f));
        pl += (same && (ri != cj)) ? sp : 0.0f;   // diag handled in finalize
        nl += same ? 0.0f : sp;
      }
#pragma unroll
      for (int s = 8; s; s >>= 1) {
        pl += __shfl_xor(pl, s, 64);
        nl += __shfl_xor(nl, s, 64);
      }
      if (lr == 0) { red[wC][rloc][0] = pl; red[wC][rloc][1] = nl; }
    }
  }
  __syncthreads();
  if (t < TILE * 2) {
    const int row = t >> 1, v = t & 1;
    part[((size_t)blockIdx.x * NN + (rowBase + row)) * 2 + v] =
        red[0][row][v] + red[1][row][v];
  }
}

// ---------------------------------------------------------------------------
// finalize 1: per-row combine over 32 chunks + analytic diagonal + histogram
// counts; row 4095 emits last_pos/last_neg from the f32 partials.
__global__ __launch_bounds__(256) void fin1_kernel(
    const float* __restrict__ part, const float* __restrict__ dval,
    const float* __restrict__ dinc, const int* __restrict__ hist,
    const int* __restrict__ tg, const float* __restrict__ lrp,
    float* __restrict__ row_loss, float* __restrict__ inv,
    float* __restrict__ out) {
  const int r = blockIdx.x * 256 + threadIdx.x;
  float pl = 0.f, nl = 0.f;
  for (int c = 0; c < NCH; ++c) {
    const float* p = part + ((size_t)c * NN + r) * 2;
    pl += p[0]; nl += p[1];
  }
  const float inc = dinc[r], dv = dval[r];
  const float scnt = (float)(hist[tg[r]] - 1);   // off-diag same-class count
  const float pos_cnt = scnt + inc;
  const float pos_sum = pl + inc * softplus_fast(1.0f - 2.0f * dv);
  const float pos_loss = pos_sum / fmaxf(pos_cnt, 1.0f);
  const float neg_cnt = 4095.0f - scnt;
  const float neg_loss = nl / fmaxf(neg_cnt, 1.0f);
  const bool valid = neg_cnt > 0.0f;
  row_loss[r] = valid ? (pos_loss + neg_loss) : 0.0f;
  inv[r] = valid ? 0.0f : 1.0f;
  if (r == NN - 1) {
    float ss = 0.f, ns = 0.f;
    for (int c = 0; c < 16; ++c) { ss += lrp[c * 2]; ns += lrp[c * 2 + 1]; }
    out[2] = (ss + inc * dv) / fmaxf(pos_cnt, 1.0f);
    out[3] = ns / fmaxf(neg_cnt, 1.0f);
  }
}

// finalize 2: deterministic tree reduce of row losses.
__global__ __launch_bounds__(1024) void fin2_kernel(
    const float* __restrict__ row_loss, const float* __restrict__ inv,
    float* __restrict__ out) {
  __shared__ double sl[1024];
  __shared__ double si[1024];
  const int t = threadIdx.x;
  double l = 0.0, iv = 0.0;
  for (int r = t; r < NN; r += 1024) { l += row_loss[r]; iv += inv[r]; }
  sl[t] = l; si[t] = iv;
  __syncthreads();
  for (int s = 512; s; s >>= 1) {
    if (t < s) { sl[t] += sl[t + s]; si[t] += si[t + s]; }
    __syncthreads();
  }
  if (t == 0) {
    out[0] = (float)(sl[0] / NN);
    out[1] = (float)(si[0] / NN);
  }
}

extern "C" void kernel_launch(void* const* d_in, const int* in_sizes, int n_in,
                              void* d_out, int out_size, void* d_ws, size_t ws_size,
                              hipStream_t stream) {
  const float* x = (const float*)d_in[0];
  const int* tg = (const int*)d_in[1];
  float* out = (float*)d_out;
  char* ws = (char*)d_ws;

  u16*   xbf      = (u16*)ws;
  float* dval     = (float*)(ws + OFF_DVAL);
  float* dinc     = (float*)(ws + OFF_DINC);
  int*   hist     = (int*)(ws + OFF_HIST);
  float* lrp      = (float*)(ws + OFF_LRP);
  float* part     = (float*)(ws + OFF_PART);
  float* row_loss = (float*)(ws + OFF_RL);
  float* inv      = (float*)(ws + OFF_INV);

  prep_kernel<<<NN / 4 + 1 + 16, 256, 0, stream>>>(x, tg, xbf, dval, dinc, hist, lrp);
  dim3 grid(NCH, NCH);
  sim_kernel<<<grid, 256, 0, stream>>>(xbf, tg, part);
  fin1_kernel<<<NN / 256, 256, 0, stream>>>(part, dval, dinc, hist, tg, lrp,
                                            row_loss, inv, out);
  fin2_kernel<<<1, 1024, 0, stream>>>(row_loss, inv, out);
}

// Round 3
// 64.626 us; speedup vs baseline: 1.6747x; 1.0567x over previous
//
#include <hip/hip_runtime.h>
#include <hip/hip_bf16.h>

#define NN 4096
#define DD 512
#define TILE 128
#define NCH (NN / TILE)                 // 32 tile-chunks per side
#define NTRI (NCH * (NCH + 1) / 2)      // 528 upper-triangle blocks

typedef unsigned short u16;
typedef __attribute__((ext_vector_type(4))) float f32x4;
typedef __attribute__((ext_vector_type(8))) short bf16x8;

// ws layout (bytes):
#define OFF_DVAL ((size_t)NN * DD * 2)                 // xbf: NN*DD u16
#define OFF_DINC (OFF_DVAL + (size_t)NN * 4)           // exact diag f32
#define OFF_HIST (OFF_DINC + (size_t)NN * 4)           // include flag f32
#define OFF_LRP  (OFF_HIST + 256 * 4)                  // class histogram i32
#define OFF_PART (OFF_LRP + 16 * 2 * 4)                // last-row partials
#define OFF_BS   (OFF_PART + (size_t)NCH * NN * 2 * 4) // per-chunk {pl,nl}
// OFF_BS: 16 blocks x {loss,inv} f64
// total ~5.3 MB

__device__ __forceinline__ float softplus_fast(float z) {
  // ln(1+e^z); z in [-63, 23] here -> no overflow; 2 native transcendentals.
  return __logf(1.0f + __expf(z));
}

__device__ __forceinline__ void gload_lds16(const u16* g, void* l) {
  __builtin_amdgcn_global_load_lds(
      (const __attribute__((address_space(1))) void*)g,
      (__attribute__((address_space(3))) void*)l, 16, 0, 0);
}

// ---------------------------------------------------------------------------
// prep (3 roles by blockIdx):
//   [0, NN/4):   x -> bf16 + exact f64 row sum-of-squares (diag decision)
//   NN/4:        class histogram (LDS int atomics = deterministic)
//   NN/4+1 ...:  last-row (4095) f32 sim partial sums {ss, ns}
__global__ __launch_bounds__(256) void prep_kernel(
    const float* __restrict__ x, const int* __restrict__ tg,
    u16* __restrict__ xbf, float* __restrict__ dval, float* __restrict__ dinc,
    int* __restrict__ hist, float* __restrict__ lrp) {
  const int bid = blockIdx.x;
  const int t = threadIdx.x;
  if (bid < NN / 4) {
    const int wid = t >> 6, lane = t & 63;
    const int row = bid * 4 + wid;
    const float* xr = x + (size_t)row * DD;
    u16* xb = xbf + (size_t)row * DD;
    double s = 0.0;
#pragma unroll
    for (int c = 0; c < DD / 64; ++c) {
      float v = xr[c * 64 + lane];
      s += (double)v * (double)v;
      __hip_bfloat16 b = __float2bfloat16(v);
      xb[c * 64 + lane] = *reinterpret_cast<const u16*>(&b);
    }
#pragma unroll
    for (int m = 32; m; m >>= 1) s += __shfl_xor(s, m, 64);
    if (lane == 0) {
      float sf = (float)s;
      dval[row] = sf;
      dinc[row] = (sf < 1.0f) ? 1.0f : 0.0f;  // ref: pos includes diag iff sim<1
    }
  } else if (bid == NN / 4) {
    __shared__ int h[256];
    h[t] = 0;
    __syncthreads();
    const int base = t * (NN / 256);
#pragma unroll
    for (int k = 0; k < NN / 256; ++k) atomicAdd(&h[tg[base + k]], 1);
    __syncthreads();
    hist[t] = h[t];
  } else {
    const int b = bid - (NN / 4 + 1);
    const int j = b * 256 + t;
    const int tl = tg[NN - 1];
    const f32x4* xr = (const f32x4*)(x + (size_t)(NN - 1) * DD);
    const f32x4* xj = (const f32x4*)(x + (size_t)j * DD);
    f32x4 av = {0.f, 0.f, 0.f, 0.f};
#pragma unroll 4
    for (int k = 0; k < DD / 4; ++k) av += xr[k] * xj[k];
    const float sim = av[0] + av[1] + av[2] + av[3];
    const bool same = (tg[j] == tl);
    float ss = (same && j != NN - 1) ? sim : 0.0f;
    float ns = !same ? sim : 0.0f;
#pragma unroll
    for (int m = 32; m; m >>= 1) {
      ss += __shfl_xor(ss, m, 64);
      ns += __shfl_xor(ns, m, 64);
    }
    __shared__ float r2[2][4];
    if ((t & 63) == 0) { r2[0][t >> 6] = ss; r2[1][t >> 6] = ns; }
    __syncthreads();
    if (t == 0) {
      lrp[b * 2 + 0] = r2[0][0] + r2[0][1] + r2[0][2] + r2[0][3];
      lrp[b * 2 + 1] = r2[1][0] + r2[1][1] + r2[1][2] + r2[1][3];
    }
  }
}

// ---------------------------------------------------------------------------
// main: upper-triangle 128x128 tiles. Off-diagonal blocks emit BOTH row sums
// (tile bi) and column sums (tile bj, by symmetry of sim) of the masked
// softplus values. One writer per (chunk,row) slot -> deterministic.
__global__ __launch_bounds__(256) void sim_kernel(
    const u16* __restrict__ xbf, const int* __restrict__ tg,
    float* __restrict__ part) {
  __shared__ u16 sA[TILE * 32];   // [128 rows][32 k] bf16
  __shared__ u16 sB[TILE * 32];
  __shared__ float red[2][TILE][2];    // row sums, split by wC
  __shared__ float redc[2][TILE][2];   // col sums, split by wR

  // triangular decode: bi <= bj
  int l = blockIdx.x, bi = 0, span = NCH;
  while (l >= span) { l -= span; ++bi; --span; }
  const int bj = bi + l;
  const bool offdiag = (bi != bj);

  const int t = threadIdx.x;
  const int lane = t & 63, wid = t >> 6;
  const int wR = wid >> 1, wC = wid & 1;          // 2x2 wave grid, 64x64 each
  const int q = lane >> 4, lr = lane & 15;
  const int rowBase = bi * TILE, colBase = bj * TILE;

  f32x4 acc[4][4] = {};

  const int r0 = t >> 2;            // 0..63
  const int kk = (t & 3) * 8;       // 0,8,16,24

  for (int kb = 0; kb < DD; kb += 32) {
    const u16* gA = xbf + (size_t)(rowBase + r0) * DD + kb + kk;
    const u16* gB = xbf + (size_t)(colBase + r0) * DD + kb + kk;
    char* lA = (char*)sA + wid * 1024;            // wave-uniform base + lane*16
    char* lB = (char*)sB + wid * 1024;
    gload_lds16(gA, lA);
    gload_lds16(gA + 64 * DD, lA + 4096);
    gload_lds16(gB, lB);
    gload_lds16(gB + 64 * DD, lB + 4096);
    __syncthreads();

    bf16x8 af[4], bg[4];
#pragma unroll
    for (int m = 0; m < 4; ++m) {
      af[m] = *reinterpret_cast<const bf16x8*>(&sA[(wR * 64 + m * 16 + lr) * 32 + q * 8]);
      bg[m] = *reinterpret_cast<const bf16x8*>(&sB[(wC * 64 + m * 16 + lr) * 32 + q * 8]);
    }
#pragma unroll
    for (int m = 0; m < 4; ++m)
#pragma unroll
      for (int n = 0; n < 4; ++n)
        acc[m][n] = __builtin_amdgcn_mfma_f32_16x16x32_bf16(af[m], bg[n], acc[m][n], 0, 0, 0);
    __syncthreads();
  }

  // epilogue: C/D layout col=lane&15, row=(lane>>4)*4+j (m89-verified).
  int tc[4];
#pragma unroll
  for (int n = 0; n < 4; ++n) tc[n] = tg[colBase + wC * 64 + n * 16 + lr];

  float colP[4] = {0.f, 0.f, 0.f, 0.f}, colN[4] = {0.f, 0.f, 0.f, 0.f};

#pragma unroll
  for (int m = 0; m < 4; ++m) {
#pragma unroll
    for (int j = 0; j < 4; ++j) {
      const int rloc = wR * 64 + m * 16 + q * 4 + j;
      const int ri = rowBase + rloc;
      const int trr = tg[ri];
      float pl = 0.f, nl = 0.f;
#pragma unroll
      for (int n = 0; n < 4; ++n) {
        const float sim = acc[m][n][j];
        const int cj = colBase + wC * 64 + n * 16 + lr;
        const bool same = (trr == tc[n]);
        const float c = same ? -2.0f : 40.0f;
        const float sp = softplus_fast(c * (sim - 0.5f));
        const float pv = (same && (ri != cj)) ? sp : 0.0f;  // diag analytic
        const float nv = same ? 0.0f : sp;
        pl += pv; nl += nv;
        colP[n] += pv; colN[n] += nv;
      }
#pragma unroll
      for (int s = 8; s; s >>= 1) {
        pl += __shfl_xor(pl, s, 64);
        nl += __shfl_xor(nl, s, 64);
      }
      if (lr == 0) { red[wC][rloc][0] = pl; red[wC][rloc][1] = nl; }
    }
  }

  if (offdiag) {
#pragma unroll
    for (int n = 0; n < 4; ++n) {
      colP[n] += __shfl_xor(colP[n], 16, 64);
      colP[n] += __shfl_xor(colP[n], 32, 64);
      colN[n] += __shfl_xor(colN[n], 16, 64);
      colN[n] += __shfl_xor(colN[n], 32, 64);
      if (q == 0) {
        const int cloc = wC * 64 + n * 16 + lr;
        redc[wR][cloc][0] = colP[n];
        redc[wR][cloc][1] = colN[n];
      }
    }
  }
  __syncthreads();

  if (t < TILE * 2) {
    const int row = t >> 1, v = t & 1;
    // row sums -> tile bi, chunk bj
    part[((size_t)bj * NN + (rowBase + row)) * 2 + v] =
        red[0][row][v] + red[1][row][v];
    // col sums -> tile bj, chunk bi (symmetry)
    if (offdiag) {
      part[((size_t)bi * NN + (colBase + row)) * 2 + v] =
          redc[0][row][v] + redc[1][row][v];
    }
  }
}

// ---------------------------------------------------------------------------
// finalize 1: per-row combine over 32 chunks + analytic diagonal + histogram
// counts; block-level f64 tree reduce -> 16 partials. Row 4095 emits
// last_pos/last_neg from the f32 partials.
__global__ __launch_bounds__(256) void fin1_kernel(
    const float* __restrict__ part, const float* __restrict__ dval,
    const float* __restrict__ dinc, const int* __restrict__ hist,
    const int* __restrict__ tg, const float* __restrict__ lrp,
    double* __restrict__ bsums, float* __restrict__ out) {
  const int t = threadIdx.x;
  const int r = blockIdx.x * 256 + t;
  float pl = 0.f, nl = 0.f;
  for (int c = 0; c < NCH; ++c) {
    const float* p = part + ((size_t)c * NN + r) * 2;
    pl += p[0]; nl += p[1];
  }
  const float inc = dinc[r], dv = dval[r];
  const float scnt = (float)(hist[tg[r]] - 1);   // off-diag same-class count
  const float pos_cnt = scnt + inc;
  const float pos_sum = pl + inc * softplus_fast(1.0f - 2.0f * dv);
  const float pos_loss = pos_sum / fmaxf(pos_cnt, 1.0f);
  const float neg_cnt = 4095.0f - scnt;
  const float neg_loss = nl / fmaxf(neg_cnt, 1.0f);
  const bool valid = neg_cnt > 0.0f;

  __shared__ double sl[256];
  __shared__ double si[256];
  sl[t] = valid ? (double)(pos_loss + neg_loss) : 0.0;
  si[t] = valid ? 0.0 : 1.0;
  __syncthreads();
  for (int s = 128; s; s >>= 1) {
    if (t < s) { sl[t] += sl[t + s]; si[t] += si[t + s]; }
    __syncthreads();
  }
  if (t == 0) { bsums[blockIdx.x * 2] = sl[0]; bsums[blockIdx.x * 2 + 1] = si[0]; }

  if (r == NN - 1) {
    float ss = 0.f, ns = 0.f;
    for (int c = 0; c < 16; ++c) { ss += lrp[c * 2]; ns += lrp[c * 2 + 1]; }
    out[2] = (ss + inc * dv) / fmaxf(pos_cnt, 1.0f);
    out[3] = ns / fmaxf(neg_cnt, 1.0f);
  }
}

// finalize 2: tiny — sum 16 block partials.
__global__ __launch_bounds__(64) void fin2_kernel(
    const double* __restrict__ bsums, float* __restrict__ out) {
  if (threadIdx.x == 0) {
    double l = 0.0, iv = 0.0;
    for (int b = 0; b < NN / 256; ++b) { l += bsums[b * 2]; iv += bsums[b * 2 + 1]; }
    out[0] = (float)(l / NN);
    out[1] = (float)(iv / NN);
  }
}

extern "C" void kernel_launch(void* const* d_in, const int* in_sizes, int n_in,
                              void* d_out, int out_size, void* d_ws, size_t ws_size,
                              hipStream_t stream) {
  const float* x = (const float*)d_in[0];
  const int* tg = (const int*)d_in[1];
  float* out = (float*)d_out;
  char* ws = (char*)d_ws;

  u16*    xbf  = (u16*)ws;
  float*  dval = (float*)(ws + OFF_DVAL);
  float*  dinc = (float*)(ws + OFF_DINC);
  int*    hist = (int*)(ws + OFF_HIST);
  float*  lrp  = (float*)(ws + OFF_LRP);
  float*  part = (float*)(ws + OFF_PART);
  double* bs   = (double*)(ws + OFF_BS);

  prep_kernel<<<NN / 4 + 1 + 16, 256, 0, stream>>>(x, tg, xbf, dval, dinc, hist, lrp);
  sim_kernel<<<NTRI, 256, 0, stream>>>(xbf, tg, part);
  fin1_kernel<<<NN / 256, 256, 0, stream>>>(part, dval, dinc, hist, tg, lrp, bs, out);
  fin2_kernel<<<1, 64, 0, stream>>>(bs, out);
}